// Round 12
// baseline (277.846 us; speedup 1.0000x reference)
//
#include <hip/hip_runtime.h>
#include <hip/hip_bf16.h>

constexpr int NROW = 8192;
constexpr int INF  = 256;
constexpr int OUTF = 128;
constexpr int KSPLIT = 8;
constexpr int KCHUNK = NROW / KSPLIT; // 1024
#define LOG2E 1.4426950408889634f

typedef __bf16 bf16x8 __attribute__((ext_vector_type(8)));
typedef float  f32x4  __attribute__((ext_vector_type(4)));
typedef int    i32x4  __attribute__((ext_vector_type(4)));

// ---------------------------------------------------------------------------
// k1: h = x@W (f32 accum); f1 = (h@a1)*log2e, f2 = (h@a2)*log2e; ht = h^T bf16
// grid: NROW/32 blocks, 256 threads
// ---------------------------------------------------------------------------
__global__ __launch_bounds__(256) void k1(const float* __restrict__ x,
                                          const float* __restrict__ W,
                                          const float* __restrict__ a,
                                          __bf16* __restrict__ ht,
                                          float* __restrict__ f1,
                                          float* __restrict__ f2) {
  __shared__ float xs[32][INF];   // 32 KB
  __shared__ float hs[32][OUTF];  // 16 KB
  const int t  = threadIdx.x;
  const int i0 = blockIdx.x * 32;

  const f32x4* xsrc = reinterpret_cast<const f32x4*>(x + (size_t)i0 * INF);
  f32x4* xdst = reinterpret_cast<f32x4*>(&xs[0][0]);
  #pragma unroll
  for (int u = 0; u < (32 * INF / 4) / 256; ++u)
    xdst[u * 256 + t] = xsrc[u * 256 + t];
  __syncthreads();

  const int c  = t & 127;
  const int rg = t >> 7;  // 0/1 -> rows rg*16 .. rg*16+15
  float acc[16];
  #pragma unroll
  for (int r = 0; r < 16; ++r) acc[r] = 0.f;
  for (int k = 0; k < INF; ++k) {
    float wv = W[k * OUTF + c];
    #pragma unroll
    for (int r = 0; r < 16; ++r) acc[r] += xs[rg * 16 + r][k] * wv;
  }
  #pragma unroll
  for (int r = 0; r < 16; ++r) hs[rg * 16 + r][c] = acc[r];
  __syncthreads();

  const int wv = t >> 6, lane = t & 63;
  for (int r = wv; r < 32; r += 4) {
    float h0 = hs[r][lane * 2], h1 = hs[r][lane * 2 + 1];
    float s1 = h0 * a[lane * 2] + h1 * a[lane * 2 + 1];
    float s2 = h0 * a[OUTF + lane * 2] + h1 * a[OUTF + lane * 2 + 1];
    #pragma unroll
    for (int off = 32; off; off >>= 1) {
      s1 += __shfl_down(s1, off);
      s2 += __shfl_down(s2, off);
    }
    if (lane == 0) { f1[i0 + r] = s1 * LOG2E; f2[i0 + r] = s2 * LOG2E; }
  }

  const int col = t >> 1, seg = t & 1;
  bf16x8 v0, v1;
  #pragma unroll
  for (int r = 0; r < 8; ++r) v0[r] = (__bf16)hs[seg * 16 + r][col];
  #pragma unroll
  for (int r = 0; r < 8; ++r) v1[r] = (__bf16)hs[seg * 16 + 8 + r][col];
  __bf16* hdst = ht + (size_t)col * NROW + i0 + seg * 16;
  *reinterpret_cast<bf16x8*>(hdst)     = v0;
  *reinterpret_cast<bf16x8*>(hdst + 8) = v1;
}

// ---------------------------------------------------------------------------
// katt2: one row per block, 8192 blocks. Slimmed: no mask / no s output —
// kpv now consumes the att matrix directly.
// Phase 1 (pure READ): 8 adj NT loads + 8 f2 loads (kept in registers).
// Phase 1.5: block sum-reduce only.
// Phase 2 (pure WRITE): recompute p from register fv; zero loads between
// stores so the in-order vmcnt queue never forces a store drain.
// grid: NROW blocks, 256 threads
// ---------------------------------------------------------------------------
__global__ __launch_bounds__(256) void katt2(const int* __restrict__ adj,
                                             const float* __restrict__ f1,
                                             const float* __restrict__ f2,
                                             float* __restrict__ att) {
  const int i = blockIdx.x;
  const int t = threadIdx.x;
  const int lane = t & 63, wv = t >> 6;
  const float f1i = f1[i];
  const i32x4* arow = reinterpret_cast<const i32x4*>(adj + (size_t)i * NROW);
  const f32x4* f2v  = reinterpret_cast<const f32x4*>(f2);

  // ---- phase 1: pure read stream ----
  unsigned mynibs = 0;
  float acc = 0.f;
  f32x4 fv[8];
  #pragma unroll
  for (int it = 0; it < 8; ++it) {
    i32x4 av = __builtin_nontemporal_load(arow + it * 256 + t);
    fv[it] = f2v[it * 256 + t];
    unsigned nib = (av[0] > 0) | ((av[1] > 0) << 1) | ((av[2] > 0) << 2) |
                   ((av[3] > 0) << 3);
    mynibs |= nib << (it * 4);
    #pragma unroll
    for (int b = 0; b < 4; ++b) {
      float e = f1i + fv[it][b];
      e = e > 0.f ? e : 0.01f * e;
      acc += ((nib >> b) & 1u) ? __builtin_exp2f(e) : 0.f;
    }
  }

  // ---- phase 1.5: row-sum reduction ----
  #pragma unroll
  for (int off = 32; off; off >>= 1) acc += __shfl_down(acc, off);
  __shared__ float red[4];
  if (lane == 0) red[wv] = acc;
  __syncthreads();
  const float inv_s = 1.0f / (red[0] + red[1] + red[2] + red[3]);

  // ---- phase 2: pure write stream (no loads; fv in registers) ----
  f32x4* adst = reinterpret_cast<f32x4*>(att + (size_t)i * NROW);
  #pragma unroll
  for (int it = 0; it < 8; ++it) {
    const unsigned nib = (mynibs >> (it * 4)) & 0xFu;
    f32x4 o;
    #pragma unroll
    for (int b = 0; b < 4; ++b) {
      float e = f1i + fv[it][b];
      e = e > 0.f ? e : 0.01f * e;
      o[b] = ((nib >> b) & 1u) ? __builtin_exp2f(e) * inv_s : 0.f;
    }
    adst[it * 256 + t] = o;
  }
}

// ---------------------------------------------------------------------------
// kpv: PURE GEMM out0 = att @ h. A = att rows streamed from HBM (f32 -> bf16
// cvt, already normalized -> no epilogue scaling, no exp2/mask/f2 anywhere).
// B = ht, L2-resident. A prefetched one iteration ahead — loop has zero
// stores, so the prefetch never waits behind a store drain.
// grid: (NROW/64)*KSPLIT blocks, 256 threads (4 waves; wave w -> rows w*16..)
// ---------------------------------------------------------------------------
__global__ __launch_bounds__(256, 4) void kpv(const __bf16* __restrict__ ht,
                                              const float* __restrict__ att,
                                              float* __restrict__ out0) {
  const int mb = blockIdx.x / KSPLIT;
  const int ks = blockIdx.x % KSPLIT;
  const int t    = threadIdx.x;
  const int w    = t >> 6;
  const int lane = t & 63;
  const int lr = lane & 15;
  const int lc = lane >> 4;
  const int row0 = mb * 64 + w * 16;
  const int arow = row0 + lr;
  const int j0 = ks * KCHUNK;

  const float* abase = att + (size_t)arow * NROW + j0 + lc * 8;
  const __bf16* hbase = ht + (size_t)lr * NROW + j0 + lc * 8;

  f32x4 acc[8];
  #pragma unroll
  for (int n = 0; n < 8; ++n) acc[n] = (f32x4){0.f, 0.f, 0.f, 0.f};

  // prefetch A for kk=0: 4x f32x4 (h=0: cols +0..7, h=1: cols +32..39)
  f32x4 pa0 = *reinterpret_cast<const f32x4*>(abase);
  f32x4 pa1 = *reinterpret_cast<const f32x4*>(abase + 4);
  f32x4 pa2 = *reinterpret_cast<const f32x4*>(abase + 32);
  f32x4 pa3 = *reinterpret_cast<const f32x4*>(abase + 36);

  for (int kk = 0; kk < KCHUNK; kk += 64) {
    const f32x4 ca0 = pa0, ca1 = pa1, ca2 = pa2, ca3 = pa3;
    if (kk + 64 < KCHUNK) {
      const float* ab = abase + kk + 64;
      pa0 = *reinterpret_cast<const f32x4*>(ab);
      pa1 = *reinterpret_cast<const f32x4*>(ab + 4);
      pa2 = *reinterpret_cast<const f32x4*>(ab + 32);
      pa3 = *reinterpret_cast<const f32x4*>(ab + 36);
    }

    bf16x8 afrag[2];
    #pragma unroll
    for (int i2 = 0; i2 < 4; ++i2) {
      afrag[0][i2]     = (__bf16)ca0[i2];
      afrag[0][i2 + 4] = (__bf16)ca1[i2];
      afrag[1][i2]     = (__bf16)ca2[i2];
      afrag[1][i2 + 4] = (__bf16)ca3[i2];
    }

    #pragma unroll
    for (int n = 0; n < 8; ++n) {
      const __bf16* hb = hbase + (size_t)(n * 16) * NROW + kk;
      bf16x8 b0 = *reinterpret_cast<const bf16x8*>(hb);
      bf16x8 b1 = *reinterpret_cast<const bf16x8*>(hb + 32);
      acc[n] = __builtin_amdgcn_mfma_f32_16x16x32_bf16(afrag[0], b0, acc[n], 0, 0, 0);
      acc[n] = __builtin_amdgcn_mfma_f32_16x16x32_bf16(afrag[1], b1, acc[n], 0, 0, 0);
    }
  }

  #pragma unroll
  for (int n = 0; n < 8; ++n) {
    #pragma unroll
    for (int i2 = 0; i2 < 4; ++i2) {
      atomicAdd(&out0[(size_t)(row0 + lc * 4 + i2) * OUTF + n * 16 + lr],
                acc[n][i2]);
    }
  }
}

// ---------------------------------------------------------------------------
extern "C" void kernel_launch(void* const* d_in, const int* in_sizes, int n_in,
                              void* d_out, int out_size, void* d_ws, size_t ws_size,
                              hipStream_t stream) {
  const float* x   = (const float*)d_in[0];
  const int*   adj = (const int*)d_in[1];
  const float* W   = (const float*)d_in[2];
  const float* a   = (const float*)d_in[3];

  float* out0 = (float*)d_out;                       // 8192 x 128
  float* att  = (float*)d_out + (size_t)NROW * OUTF; // 8192 x 8192

  char* ws = (char*)d_ws;
  __bf16* ht = (__bf16*)ws;                               // 2 MB
  float* f1 = (float*)(ws + (2 << 20));
  float* f2 = (float*)(ws + (2 << 20) + 32 * 1024);

  hipMemsetAsync(out0, 0, (size_t)NROW * OUTF * sizeof(float), stream);
  k1<<<NROW / 32, 256, 0, stream>>>(x, W, a, ht, f1, f2);
  katt2<<<NROW, 256, 0, stream>>>(adj, f1, f2, att);
  kpv<<<(NROW / 64) * KSPLIT, 256, 0, stream>>>(ht, att, out0);
}